// Round 2
// baseline (109.332 us; speedup 1.0000x reference)
//
#include <hip/hip_runtime.h>
#include <math.h>

#define FW 1.0f
#define BW 1.0f
#define NW 0.1f
#define EPSV 1e-6f

#define BT  256   // threads per block
#define MPT 8     // A-points per thread (2048 per block)
#define JCH 128   // B-points staged per chunk

// Rotation from 6d, columns b1,b2,b3 (R = stack([b1,b2,b3], axis=1)).
// src @ R.T == R @ v for a row vector v.
#define COMPUTE_R(r6)                                                         \
    float a1x = (r6)[0], a1y = (r6)[1], a1z = (r6)[2];                        \
    float a2x = (r6)[3], a2y = (r6)[4], a2z = (r6)[5];                        \
    float n1 = sqrtf(a1x*a1x + a1y*a1y + a1z*a1z);                            \
    float b1x = a1x/n1, b1y = a1y/n1, b1z = a1z/n1;                           \
    float dp = b1x*a2x + b1y*a2y + b1z*a2z;                                   \
    float u2x = a2x - dp*b1x, u2y = a2y - dp*b1y, u2z = a2z - dp*b1z;         \
    float n2 = sqrtf(u2x*u2x + u2y*u2y + u2z*u2z);                            \
    float b2x = u2x/n2, b2y = u2y/n2, b2z = u2z/n2;                           \
    float b3x = b1y*b2z - b1z*b2y;                                            \
    float b3y = b1z*b2x - b1x*b2z;                                            \
    float b3z = b1x*b2y - b1y*b2x;

// ---------------------------------------------------------------------------
// chamfer_min: grid (ceil(nA/2048), nChunks, 2). Each block: 2048 A-points
// (8/thread, registers) x 128 B-points (LDS). Transform is done inline
// (redundant per block, ~0.2 ops/pair). Inner loop tracks e = t2 - 2*dot
// only (6 VALU/pair); s2-add + clamp deferred to epilogue (monotone).
// Per-chunk packed (d|idx) minima stored to part arrays — no atomics.
// ---------------------------------------------------------------------------
__global__ __launch_bounds__(BT) void chamfer_min(
    const float* __restrict__ sp, const float* __restrict__ tp,
    const float* __restrict__ trans, const float* __restrict__ r6,
    const float* __restrict__ scl,
    unsigned long long* __restrict__ part0,
    unsigned long long* __restrict__ part1,
    float* __restrict__ out, int N, int M)
{
    const int tid  = threadIdx.x;
    const int dir  = blockIdx.z;           // 0: src->tgt, 1: tgt->src
    const int nA   = dir ? M : N;
    const int nB   = dir ? N : M;
    const int jBase = blockIdx.y * JCH;
    const int aBase = blockIdx.x * (BT * MPT);

    if (dir == 0 && blockIdx.x == 0 && blockIdx.y == 0 && tid == 0)
        out[0] = 0.f;                      // finalize's atomicAdd base

    if (jBase >= nB || aBase >= nA) return;   // block-uniform

    COMPUTE_R(r6)
    float t0 = trans[0], t1 = trans[1], t2v = trans[2];
    float s0 = scl[0],  s1 = scl[1],  s2c = scl[2];

    __shared__ float4 bs[JCH];
    if (tid < JCH) {
        int j = jBase + tid; if (j >= nB) j = nB - 1;   // dup-safe (first wins)
        float x, y, z;
        if (dir == 0) { x = tp[3*j]; y = tp[3*j+1]; z = tp[3*j+2]; }
        else {
            float qx = sp[3*j]*s0, qy = sp[3*j+1]*s1, qz = sp[3*j+2]*s2c;
            x = b1x*qx + b2x*qy + b3x*qz + t0;
            y = b1y*qx + b2y*qy + b3y*qz + t1;
            z = b1z*qx + b2z*qy + b3z*qz + t2v;
        }
        bs[tid] = make_float4(x, y, z, x*x + y*y + z*z);
    }

    float cx[MPT], cy[MPT], cz[MPT], s2[MPT], best[MPT];
    int bj[MPT];
    #pragma unroll
    for (int p = 0; p < MPT; p++) {
        int ia = aBase + p*BT + tid; if (ia >= nA) ia = 0;
        float x, y, z;
        if (dir == 0) {
            float qx = sp[3*ia]*s0, qy = sp[3*ia+1]*s1, qz = sp[3*ia+2]*s2c;
            x = b1x*qx + b2x*qy + b3x*qz + t0;
            y = b1y*qx + b2y*qy + b3y*qz + t1;
            z = b1z*qx + b2z*qy + b3z*qz + t2v;
        } else { x = tp[3*ia]; y = tp[3*ia+1]; z = tp[3*ia+2]; }
        cx[p] = -2.f*x; cy[p] = -2.f*y; cz[p] = -2.f*z;
        s2[p] = x*x + y*y + z*z;
        best[p] = 3.4e38f; bj[p] = 0;
    }
    __syncthreads();

    int jLim = nB - jBase; if (jLim > JCH) jLim = JCH;
    #pragma unroll 4
    for (int j = 0; j < jLim; j++) {
        float4 b = bs[j];                    // wave-uniform -> LDS broadcast
        #pragma unroll
        for (int p = 0; p < MPT; p++) {
            float e = fmaf(cz[p], b.z, b.w);
            e = fmaf(cy[p], b.y, e);
            e = fmaf(cx[p], b.x, e);
            bool c = e < best[p];            // strict: first occurrence wins
            best[p] = c ? e : best[p];
            bj[p]   = c ? j : bj[p];
        }
    }

    unsigned long long* pbase =
        (dir == 0 ? part0 : part1) + (size_t)blockIdx.y * nA;
    #pragma unroll
    for (int p = 0; p < MPT; p++) {
        int ia = aBase + p*BT + tid;
        if (ia < nA) {
            float d = fmaxf(best[p] + s2[p], 0.f);
            unsigned long long pk =
                ((unsigned long long)__float_as_uint(d) << 32) |
                (unsigned int)(jBase + bj[p]);
            pbase[ia] = pk;
        }
    }
}

// ---------------------------------------------------------------------------
// finalize: one thread per point (both directions). Merge per-chunk packed
// minima (u64 min: equal d -> smaller idx wins = first-occurrence argmin),
// rotate normals on the fly, block-reduce, one atomicAdd per block.
// ---------------------------------------------------------------------------
__global__ __launch_bounds__(BT) void finalize(
    const unsigned long long* __restrict__ part0,
    const unsigned long long* __restrict__ part1,
    const float* __restrict__ sn, const float* __restrict__ tn,
    const float* __restrict__ r6,
    float* __restrict__ out, int N, int M, int nChunkT, int nChunkS)
{
    const int gid = blockIdx.x * BT + threadIdx.x;
    float contrib = 0.f;

    COMPUTE_R(r6)

    if (gid < N) {
        const unsigned long long* b = part0 + gid;
        unsigned long long m = ~0ull;
        for (int c = 0; c < nChunkT; c++) {
            unsigned long long v = b[(size_t)c * N];
            m = v < m ? v : m;
        }
        float d = __uint_as_float((unsigned int)(m >> 32));
        int idx = (int)(unsigned int)(m & 0xffffffffull);
        float nx = sn[3*gid], ny = sn[3*gid+1], nz = sn[3*gid+2];
        float rx = b1x*nx + b2x*ny + b3x*nz;
        float ry = b1y*nx + b2y*ny + b3y*nz;
        float rz = b1z*nx + b2z*ny + b3z*nz;
        float tx = tn[3*idx], ty = tn[3*idx+1], tz = tn[3*idx+2];
        float na = fmaxf(sqrtf(rx*rx + ry*ry + rz*rz), EPSV);
        float nb = fmaxf(sqrtf(tx*tx + ty*ty + tz*tz), EPSV);
        float cs = (rx*tx + ry*ty + rz*tz) / (na * nb);
        contrib = (FW * d + NW * (1.f - fabsf(cs))) * (1.f / N);
    } else if (gid < N + M) {
        int j = gid - N;
        const unsigned long long* b = part1 + j;
        unsigned long long m = ~0ull;
        for (int c = 0; c < nChunkS; c++) {
            unsigned long long v = b[(size_t)c * M];
            m = v < m ? v : m;
        }
        float d = __uint_as_float((unsigned int)(m >> 32));
        int idx = (int)(unsigned int)(m & 0xffffffffull);
        float tx = tn[3*j], ty = tn[3*j+1], tz = tn[3*j+2];
        float nx = sn[3*idx], ny = sn[3*idx+1], nz = sn[3*idx+2];
        float rx = b1x*nx + b2x*ny + b3x*nz;
        float ry = b1y*nx + b2y*ny + b3y*nz;
        float rz = b1z*nx + b2z*ny + b3z*nz;
        float na = fmaxf(sqrtf(tx*tx + ty*ty + tz*tz), EPSV);
        float nb = fmaxf(sqrtf(rx*rx + ry*ry + rz*rz), EPSV);
        float cs = (tx*rx + ty*ry + tz*rz) / (na * nb);
        contrib = (BW * d + NW * (1.f - fabsf(cs))) * (1.f / M);
    }

    #pragma unroll
    for (int o = 32; o > 0; o >>= 1)
        contrib += __shfl_down(contrib, o, 64);

    __shared__ float wsum[BT/64];
    if ((threadIdx.x & 63) == 0) wsum[threadIdx.x >> 6] = contrib;
    __syncthreads();
    if (threadIdx.x == 0) {
        float s = 0.f;
        #pragma unroll
        for (int w = 0; w < BT/64; w++) s += wsum[w];
        atomicAdd(out, s);
    }
}

extern "C" void kernel_launch(void* const* d_in, const int* in_sizes, int n_in,
                              void* d_out, int out_size, void* d_ws, size_t ws_size,
                              hipStream_t stream) {
    const float* sp    = (const float*)d_in[0];
    const float* tp    = (const float*)d_in[1];
    const float* sn    = (const float*)d_in[2];
    const float* tn    = (const float*)d_in[3];
    const float* trans = (const float*)d_in[4];
    const float* r6    = (const float*)d_in[5];
    const float* scl   = (const float*)d_in[6];
    float* out = (float*)d_out;

    const int N = in_sizes[0] / 3;
    const int M = in_sizes[1] / 3;

    const int nChunkT = (M + JCH - 1) / JCH;   // B-chunks, dir 0 (B = tgt)
    const int nChunkS = (N + JCH - 1) / JCH;   // B-chunks, dir 1 (B = src)

    unsigned long long* part0 = (unsigned long long*)d_ws;
    unsigned long long* part1 = part0 + (size_t)nChunkT * N;

    const int nmax = N > M ? N : M;
    const int cmax = nChunkT > nChunkS ? nChunkT : nChunkS;
    dim3 mgrid((nmax + BT*MPT - 1) / (BT*MPT), cmax, 2);
    chamfer_min<<<mgrid, BT, 0, stream>>>(sp, tp, trans, r6, scl,
                                          part0, part1, out, N, M);

    int rblocks = (N + M + BT - 1) / BT;
    finalize<<<rblocks, BT, 0, stream>>>(part0, part1, sn, tn, r6,
                                         out, N, M, nChunkT, nChunkS);
}

// Round 3
// 92.694 us; speedup vs baseline: 1.1795x; 1.1795x over previous
//
#include <hip/hip_runtime.h>
#include <math.h>

#define FW 1.0f
#define BW 1.0f
#define NW 0.1f
#define EPSV 1e-6f

#define BT  256   // threads per block
#define MPT 4     // A-points per thread (1024 per block)
#define JCH 256   // B-points staged per chunk

// Rotation from 6d, columns b1,b2,b3 (R = stack([b1,b2,b3], axis=1)).
#define COMPUTE_R(r6)                                                         \
    float a1x = (r6)[0], a1y = (r6)[1], a1z = (r6)[2];                        \
    float a2x = (r6)[3], a2y = (r6)[4], a2z = (r6)[5];                        \
    float n1 = sqrtf(a1x*a1x + a1y*a1y + a1z*a1z);                            \
    float b1x = a1x/n1, b1y = a1y/n1, b1z = a1z/n1;                           \
    float dp = b1x*a2x + b1y*a2y + b1z*a2z;                                   \
    float u2x = a2x - dp*b1x, u2y = a2y - dp*b1y, u2z = a2z - dp*b1z;         \
    float n2 = sqrtf(u2x*u2x + u2y*u2y + u2z*u2z);                            \
    float b2x = u2x/n2, b2y = u2y/n2, b2z = u2z/n2;                           \
    float b3x = b1y*b2z - b1z*b2y;                                            \
    float b3y = b1z*b2x - b1x*b2z;                                            \
    float b3z = b1x*b2y - b1y*b2x;

// ---------------------------------------------------------------------------
// Transform: y==0: src4[i]=(R*(scale*sp)+t, |.|^2), srcn4[i]=R*sn,
//                  min_s[i]=~0  (init folded in — no separate memset launch)
//            y==1: tgt4[j]=(tp, |tp|^2), min_t[j]=~0
// ---------------------------------------------------------------------------
__global__ __launch_bounds__(BT) void transform_kernel(
    const float* __restrict__ sp, const float* __restrict__ tp,
    const float* __restrict__ sn,
    const float* __restrict__ trans, const float* __restrict__ r6,
    const float* __restrict__ scl,
    float4* __restrict__ src4, float4* __restrict__ tgt4,
    float4* __restrict__ srcn4,
    unsigned long long* __restrict__ min_s,
    unsigned long long* __restrict__ min_t,
    float* __restrict__ out, int N, int M)
{
    int i = blockIdx.x * BT + threadIdx.x;

    if (blockIdx.y == 1) {
        if (i < M) {
            float x = tp[3*i], y = tp[3*i+1], z = tp[3*i+2];
            tgt4[i] = make_float4(x, y, z, x*x + y*y + z*z);
            min_t[i] = ~0ull;
        }
        return;
    }

    if (i == 0) out[0] = 0.f;     // base for reduce's atomicAdd
    if (i >= N) return;
    min_s[i] = ~0ull;

    COMPUTE_R(r6)

    float qx = sp[3*i]   * scl[0];
    float qy = sp[3*i+1] * scl[1];
    float qz = sp[3*i+2] * scl[2];
    float sx = b1x*qx + b2x*qy + b3x*qz + trans[0];
    float sy = b1y*qx + b2y*qy + b3y*qz + trans[1];
    float sz = b1z*qx + b2z*qy + b3z*qz + trans[2];
    src4[i] = make_float4(sx, sy, sz, sx*sx + sy*sy + sz*sz);

    float nx = sn[3*i], ny = sn[3*i+1], nz = sn[3*i+2];
    srcn4[i] = make_float4(b1x*nx + b2x*ny + b3x*nz,
                           b1y*nx + b2y*ny + b3y*nz,
                           b1z*nx + b2z*ny + b3z*nz, 0.f);
}

// ---------------------------------------------------------------------------
// Min kernel: block = 1024 A x 256 B(LDS). Inner loop tracks e = t2 - 2*dot
// only (6 VALU/pair); +s2 and clamp deferred to epilogue (monotone per row).
// Packed (d|idx) u64 atomicMin merges chunks (equal d -> smaller idx wins =
// first-occurrence argmin). 128 KB min arrays stay L2-resident.
// ---------------------------------------------------------------------------
__global__ __launch_bounds__(BT) void min_kernel(
    const float4* __restrict__ src4, const float4* __restrict__ tgt4,
    unsigned long long* __restrict__ min_s,
    unsigned long long* __restrict__ min_t, int N, int M)
{
    const float4* A; const float4* B; unsigned long long* outm; int nA, nB;
    if (blockIdx.z == 0) { A = src4; B = tgt4; outm = min_s; nA = N; nB = M; }
    else                 { A = tgt4; B = src4; outm = min_t; nA = M; nB = N; }

    __shared__ float4 bs[JCH];
    const int tid   = threadIdx.x;
    const int aBase = blockIdx.x * (BT * MPT);
    const int jBase = blockIdx.y * JCH;

    float cx[MPT], cy[MPT], cz[MPT], s2[MPT], best[MPT];
    int bj[MPT];
    #pragma unroll
    for (int p = 0; p < MPT; p++) {
        int ia = aBase + p*BT + tid;
        float4 a = A[ia < nA ? ia : 0];
        cx[p] = -2.f*a.x; cy[p] = -2.f*a.y; cz[p] = -2.f*a.z;
        s2[p] = a.w;
        best[p] = 3.4e38f; bj[p] = 0;
    }
    {
        int jb = jBase + tid;
        bs[tid] = B[jb < nB ? jb : nB - 1];
    }
    __syncthreads();

    int jLim = nB - jBase; if (jLim > JCH) jLim = JCH;
    if (jLim == JCH) {
        #pragma unroll 4
        for (int j = 0; j < JCH; j++) {
            float4 b = bs[j];                 // wave-uniform -> broadcast
            #pragma unroll
            for (int p = 0; p < MPT; p++) {
                float e = fmaf(cz[p], b.z, b.w);
                e = fmaf(cy[p], b.y, e);
                e = fmaf(cx[p], b.x, e);
                bool c = e < best[p];         // strict: first occurrence wins
                best[p] = c ? e : best[p];
                bj[p]   = c ? j : bj[p];
            }
        }
    } else {
        for (int j = 0; j < jLim; j++) {
            float4 b = bs[j];
            #pragma unroll
            for (int p = 0; p < MPT; p++) {
                float e = fmaf(cz[p], b.z, b.w);
                e = fmaf(cy[p], b.y, e);
                e = fmaf(cx[p], b.x, e);
                bool c = e < best[p];
                best[p] = c ? e : best[p];
                bj[p]   = c ? j : bj[p];
            }
        }
    }

    #pragma unroll
    for (int p = 0; p < MPT; p++) {
        int ia = aBase + p*BT + tid;
        if (ia < nA) {
            float d = fmaxf(best[p] + s2[p], 0.f);
            unsigned long long pk =
                ((unsigned long long)__float_as_uint(d) << 32) |
                (unsigned int)(jBase + bj[p]);
            atomicMin(&outm[ia], pk);
        }
    }
}

// ---------------------------------------------------------------------------
// Reduce: per-element loss contribution -> block reduce -> atomicAdd
// ---------------------------------------------------------------------------
__global__ __launch_bounds__(BT) void reduce_kernel(
    const unsigned long long* __restrict__ min_s,
    const unsigned long long* __restrict__ min_t,
    const float4* __restrict__ srcn4, const float* __restrict__ tn,
    float* __restrict__ out, int N, int M)
{
    int gid = blockIdx.x * BT + threadIdx.x;
    float contrib = 0.f;

    if (gid < N) {
        unsigned long long pk = min_s[gid];
        float d = __uint_as_float((unsigned int)(pk >> 32));
        int idx = (int)(unsigned int)(pk & 0xffffffffull);
        float4 nv = srcn4[gid];
        float tx = tn[3*idx], ty = tn[3*idx+1], tz = tn[3*idx+2];
        float na = fmaxf(sqrtf(nv.x*nv.x + nv.y*nv.y + nv.z*nv.z), EPSV);
        float nb = fmaxf(sqrtf(tx*tx + ty*ty + tz*tz), EPSV);
        float cs = (nv.x*tx + nv.y*ty + nv.z*tz) / (na * nb);
        contrib = (FW * d + NW * (1.f - fabsf(cs))) * (1.f / N);
    } else if (gid < N + M) {
        int j = gid - N;
        unsigned long long pk = min_t[j];
        float d = __uint_as_float((unsigned int)(pk >> 32));
        int idx = (int)(unsigned int)(pk & 0xffffffffull);
        float tx = tn[3*j], ty = tn[3*j+1], tz = tn[3*j+2];
        float4 nv = srcn4[idx];
        float na = fmaxf(sqrtf(tx*tx + ty*ty + tz*tz), EPSV);
        float nb = fmaxf(sqrtf(nv.x*nv.x + nv.y*nv.y + nv.z*nv.z), EPSV);
        float cs = (tx*nv.x + ty*nv.y + tz*nv.z) / (na * nb);
        contrib = (BW * d + NW * (1.f - fabsf(cs))) * (1.f / M);
    }

    #pragma unroll
    for (int o = 32; o > 0; o >>= 1)
        contrib += __shfl_down(contrib, o, 64);

    __shared__ float wsum[BT/64];
    if ((threadIdx.x & 63) == 0) wsum[threadIdx.x >> 6] = contrib;
    __syncthreads();
    if (threadIdx.x == 0) {
        float s = 0.f;
        #pragma unroll
        for (int w = 0; w < BT/64; w++) s += wsum[w];
        atomicAdd(out, s);
    }
}

extern "C" void kernel_launch(void* const* d_in, const int* in_sizes, int n_in,
                              void* d_out, int out_size, void* d_ws, size_t ws_size,
                              hipStream_t stream) {
    const float* sp    = (const float*)d_in[0];
    const float* tp    = (const float*)d_in[1];
    const float* sn    = (const float*)d_in[2];
    const float* tn    = (const float*)d_in[3];
    const float* trans = (const float*)d_in[4];
    const float* r6    = (const float*)d_in[5];
    const float* scl   = (const float*)d_in[6];
    float* out = (float*)d_out;

    const int N = in_sizes[0] / 3;
    const int M = in_sizes[1] / 3;

    char* ws = (char*)d_ws;
    float4* src4  = (float4*)(ws);
    float4* tgt4  = (float4*)(ws + (size_t)16*N);
    float4* srcn4 = (float4*)(ws + (size_t)16*N + (size_t)16*M);
    unsigned long long* min_s =
        (unsigned long long*)(ws + (size_t)32*N + (size_t)16*M);
    unsigned long long* min_t = min_s + N;

    int nmax = N > M ? N : M;
    dim3 tgrid((nmax + BT - 1) / BT, 2);
    transform_kernel<<<tgrid, BT, 0, stream>>>(sp, tp, sn, trans, r6, scl,
                                               src4, tgt4, srcn4,
                                               min_s, min_t, out, N, M);

    dim3 mgrid((N + BT*MPT - 1) / (BT*MPT), (M + JCH - 1) / JCH, 2);
    min_kernel<<<mgrid, BT, 0, stream>>>(src4, tgt4, min_s, min_t, N, M);

    int rblocks = (N + M + BT - 1) / BT;
    reduce_kernel<<<rblocks, BT, 0, stream>>>(min_s, min_t, srcn4, tn, out, N, M);
}